// Round 2
// baseline (1106.020 us; speedup 1.0000x reference)
//
#include <hip/hip_runtime.h>
#include <stdint.h>

#define T_STEPS 512
#define F_IN 30
#define HID 32
#define ROWS 8    // batch rows per block; grid = B/ROWS = 512 -> 2 independent blocks/CU
#define LOG2E 1.44269504088896340736f

typedef __attribute__((ext_vector_type(8))) short short8;   // 8 bf16 (4 VGPRs)
typedef __attribute__((ext_vector_type(4))) float floatx4;  // 4 f32 acc

#define MFMA(a, b, c) __builtin_amdgcn_mfma_f32_16x16x32_bf16((a), (b), (c), 0, 0, 0)

// Raw barrier: drain LDS only (lgkmcnt), let global loads/stores ride across.
#define BAR() asm volatile("s_waitcnt lgkmcnt(0)\n\ts_barrier" ::: "memory")

__device__ __forceinline__ unsigned short f2bf(float f) {
    uint32_t u = __float_as_uint(f);
    u += 0x7fffu + ((u >> 16) & 1u);            // RTNE
    return (unsigned short)(u >> 16);
}
__device__ __forceinline__ float bf2f(unsigned short h) {
    return __uint_as_float(((uint32_t)h) << 16);
}
// packed f32->bf16 RTNE, single VALU op (gfx950)
__device__ __forceinline__ uint32_t cvtpk(float a, float b) {
    uint32_t r;
    asm("v_cvt_pk_bf16_f32 %0, %1, %2" : "=v"(r) : "v"(a), "v"(b));
    return r;
}
__device__ __forceinline__ float rcp_f(float x) { return __builtin_amdgcn_rcpf(x); }

__device__ __forceinline__ void loadx8(float (&d)[8], const float* p, bool tail) {
    float2 a0 = *(const float2*)(p + 0);
    float2 a1 = *(const float2*)(p + 2);
    float2 a2 = *(const float2*)(p + 4);
    float2 a3 = make_float2(0.f, 0.f);
    if (!tail) a3 = *(const float2*)(p + 6);     // quad3 covers features 24..29 + zero pad
    d[0]=a0.x; d[1]=a0.y; d[2]=a1.x; d[3]=a1.y;
    d[4]=a2.x; d[5]=a2.y; d[6]=a3.x; d[7]=a3.y;
}

__global__ __launch_bounds__(512, 4)
void lstm_fused_kernel(const float* __restrict__ x, const float* __restrict__ h0,
                       const float* __restrict__ c0, const float* __restrict__ W_ih,
                       const float* __restrict__ W_hh, const float* __restrict__ b_ih,
                       const float* __restrict__ b_hh, const float* __restrict__ W_all,
                       const float* __restrict__ b_all, const float* __restrict__ W_pos,
                       const float* __restrict__ b_pos, const float* __restrict__ W_lv,
                       const float* __restrict__ b_lv, float* __restrict__ pos_out,
                       float* __restrict__ lv_out, float* __restrict__ hT_out,
                       float* __restrict__ cT_out)
{
    const int tid  = threadIdx.x;
    const int wv   = tid >> 6;        // wave 0..7 == n-tile; gate type = wv>>1
    const int lane = tid & 63;
    const int quad = lane >> 4;
    const int l15  = lane & 15;
    const int rowbase = blockIdx.x * ROWS;

    __shared__ float gbuf[ROWS][132];                        // [row][gate 0..127], +4 pad
    // h state, bf16 hi/lo in SEPARATE arrays -> ds_read_b128 gives MFMA frags with ZERO unpack.
    // 16 rows declared; rows ROWS..15 are zeroed once and only read (dead M-tile rows).
    __shared__ __align__(16) unsigned short hbh[16][40];
    __shared__ __align__(16) unsigned short hbl[16][40];
    // masked output (out = m ? h_new : 0) hi/lo: A-operand of the head MFMA
    __shared__ __align__(16) unsigned short obh[16][40];
    __shared__ __align__(16) unsigned short obl[16][40];

    // ---- B-fragments for this wave's n-tile (gate column gcol) ----
    // exp2 folding: scale W and bias by -log2e (sigmoid gates) / -2*log2e (g gate),
    // so activation = rcp(1+exp2(acc)) (resp. fma(2,rcp,-1)) with NO fp32 division.
    const bool  is_g   = ((wv >> 1) == 2);
    const float gscale = (is_g ? -2.0f : -1.0f) * LOG2E;
    const int gcol = wv * 16 + l15;
    short8 wxh, wxl, whh, whl;
#pragma unroll
    for (int j = 0; j < 8; ++j) {
        const int k = quad * 8 + j;
        float wx = (k < F_IN) ? W_ih[gcol * F_IN + k] * gscale : 0.0f;
        unsigned short hx = f2bf(wx);
        wxh[j] = (short)hx; wxl[j] = (short)f2bf(wx - bf2f(hx));
        float wh = W_hh[gcol * HID + k] * gscale;
        unsigned short hh = f2bf(wh);
        whh[j] = (short)hh; whl[j] = (short)f2bf(wh - bf2f(hh));
    }
    const float bias = (b_ih[gcol] + b_hh[gcol]) * gscale;

    // ---- head B-fragments (used by wave 0): col 0 = pos0, 1 = pos1, 2 = leave ----
    // Wc[g][k] = sum_o W_pos[g][o] * W_all[o][k]  (hi/lo split for fp32-grade dot)
    short8 wph, wpl;
#pragma unroll
    for (int j = 0; j < 8; ++j) {
        const int k = quad * 8 + j;
        float w = 0.0f;
        if (l15 == 0) { for (int o = 0; o < HID; ++o) w += W_pos[o] * W_all[o * HID + k]; }
        else if (l15 == 1) { for (int o = 0; o < HID; ++o) w += W_pos[HID + o] * W_all[o * HID + k]; }
        else if (l15 == 2) { w = W_lv[k]; }
        unsigned short hw_ = f2bf(w);
        wph[j] = (short)hw_; wpl[j] = (short)f2bf(w - bf2f(hw_));
    }
    float bc0 = b_pos[0], bc1 = b_pos[1];
    for (int o = 0; o < HID; ++o) { bc0 += W_pos[o] * b_all[o]; bc1 += W_pos[HID + o] * b_all[o]; }
    const float blv = b_lv[0];

    // ---- update role: row = wave index (0..7), lanes 0..31 = hidden unit ----
    const int um = wv;
    const int uj = lane & 31;
    const bool uact = (lane < 32);
    const int urow = rowbase + um;                 // always < B
    float c_st = 0.f, h_st = 0.f;
    if (uact) {
        c_st = c0[(size_t)urow * HID + uj];
        h_st = h0[(size_t)urow * HID + uj];
    }

    // zero all state rows once (incl. dead rows ROWS..15 read by A-frag lanes l15>=ROWS)
    for (int i = tid; i < 16 * 40; i += 512) {
        ((unsigned short*)hbh)[i] = 0; ((unsigned short*)hbl)[i] = 0;
        ((unsigned short*)obh)[i] = 0; ((unsigned short*)obl)[i] = 0;
    }
    BAR();
    if (uact) {   // init live h state
        unsigned short ph = f2bf(h_st);
        hbh[um][uj] = ph;
        hbl[um][uj] = f2bf(h_st - bf2f(ph));
    }

    // x A-fragment pointers: live lanes l15 < ROWS read row rowbase+l15, feat quad*8..+7
    const bool  xact  = (l15 < ROWS);
    const float* xlane = x + (size_t)(rowbase + (l15 & (ROWS - 1))) * T_STEPS * F_IN + quad * 8;
    const float* mptr  = x + (size_t)urow * T_STEPS * F_IN + (F_IN - 1);
    const bool tail = (quad == 3);

    // depth-4 register prefetch ring (dead lanes keep zeros)
    float xr0[8] = {0,0,0,0,0,0,0,0}, xr1[8] = {0,0,0,0,0,0,0,0};
    float xr2[8] = {0,0,0,0,0,0,0,0}, xr3[8] = {0,0,0,0,0,0,0,0};
    float mr0, mr1, mr2, mr3;
    if (xact) {
        loadx8(xr0, xlane + 0 * F_IN, tail);
        loadx8(xr1, xlane + 1 * F_IN, tail);
        loadx8(xr2, xlane + 2 * F_IN, tail);
        loadx8(xr3, xlane + 3 * F_IN, tail);
    }
    mr0 = mptr[0 * F_IN];  mr1 = mptr[1 * F_IN];
    mr2 = mptr[2 * F_IN];  mr3 = mptr[3 * F_IN];

    BAR();

    auto step = [&](int t, float (&xr)[8], float& mr) {
        // snapshot mask before the ring slot is overwritten
        const float mcur = mr;
        // convert current x via packed bf16 cvt
        union XU { uint32_t u[4]; short8 s; } xu;
        xu.u[0] = cvtpk(xr[0], xr[1]);
        xu.u[1] = cvtpk(xr[2], xr[3]);
        xu.u[2] = cvtpk(xr[4], xr[5]);
        xu.u[3] = cvtpk(xr[6], xr[7]);
        const short8 xah = xu.s;
        // h fragments: direct b128 reads, no unpack (dead rows read zeros)
        const short8 hah = *(const short8*)&hbh[l15][quad * 8];
        const short8 hal = *(const short8*)&hbl[l15][quad * 8];
        // wave0: issue head (t-1) operand reads early so latency hides under gate MFMAs
        const bool do_head = (wv == 0) && (t > 0);
        short8 oah, oal;
        if (do_head) {
            oah = *(const short8*)&obh[l15][quad * 8];
            oal = *(const short8*)&obl[l15][quad * 8];
        }
        // prefetch t+4 into this ring slot (rides across raw barriers)
        {
            const int tp = (t + 4 < T_STEPS) ? t + 4 : (T_STEPS - 1);
            if (xact) loadx8(xr, xlane + tp * F_IN, tail);
            mr = mptr[tp * F_IN];
        }
        // two independent MFMA chains, re-joined at activation
        floatx4 accx = {bias, bias, bias, bias};
        accx = MFMA(xah, wxh, accx);
        accx = MFMA(xah, wxl, accx);
        floatx4 acch = {0.f, 0.f, 0.f, 0.f};
        acch = MFMA(hah, whh, acch);
        acch = MFMA(hal, whh, acch);
        acch = MFMA(hah, whl, acch);
        // activation for live rows only (quads 0,1 hold C rows 0..7)
        if (quad < 2) {
#pragma unroll
            for (int r = 0; r < 4; ++r) {
                const float a  = accx[r] + acch[r];
                const float rr = rcp_f(1.0f + exp2f(a));
                gbuf[quad * 4 + r][gcol] = is_g ? fmaf(2.0f, rr, -1.0f) : rr;
            }
        }
        // wave0: heads for step t-1 (3 MFMAs hi/lo; C rows 0..7 -> quads 0,1 store)
        if (do_head) {
            floatx4 hacc = {0.f, 0.f, 0.f, 0.f};
            hacc = MFMA(oah, wph, hacc);
            hacc = MFMA(oal, wph, hacc);
            hacc = MFMA(oah, wpl, hacc);
            if (quad < 2) {
                const size_t rb = (size_t)(rowbase + quad * 4) * T_STEPS + (t - 1);
                if (l15 == 0) {
#pragma unroll
                    for (int r = 0; r < 4; ++r) pos_out[(rb + (size_t)r * T_STEPS) * 2 + 0] = hacc[r] + bc0;
                } else if (l15 == 1) {
#pragma unroll
                    for (int r = 0; r < 4; ++r) pos_out[(rb + (size_t)r * T_STEPS) * 2 + 1] = hacc[r] + bc1;
                } else if (l15 == 2) {
#pragma unroll
                    for (int r = 0; r < 4; ++r) {
                        const float z = hacc[r] + blv;
                        lv_out[rb + (size_t)r * T_STEPS] = rcp_f(1.0f + exp2f(-LOG2E * z));
                    }
                }
            }
        }
        BAR();
        // ---- state update: wave wv owns row wv, lanes 0..31 own hidden units ----
        const float gi = gbuf[um][uj];
        const float gf = gbuf[um][32 + uj];
        const float gg = gbuf[um][64 + uj];
        const float go = gbuf[um][96 + uj];
        const float cn = gf * c_st + gi * gg;
        const float tn = fmaf(2.0f, rcp_f(1.0f + exp2f(-2.0f * LOG2E * cn)), -1.0f);
        const float hn = go * tn;
        const bool  on = (mcur == 1.0f);
        const uint32_t hi32 = cvtpk(hn, hn);
        const float res = hn - bf2f((unsigned short)hi32);
        const uint32_t lo32 = cvtpk(res, res);
        if (on) { c_st = cn; h_st = hn; }
        if (uact) {
            // out tile (masked h) always written; h state only when mask fires
            obh[um][uj] = on ? (unsigned short)hi32 : (unsigned short)0;
            obl[um][uj] = on ? (unsigned short)lo32 : (unsigned short)0;
            if (on) {
                hbh[um][uj] = (unsigned short)hi32;
                hbl[um][uj] = (unsigned short)lo32;
            }
        }
        BAR();
    };

    for (int t = 0; t < T_STEPS; t += 4) {
        step(t + 0, xr0, mr0);
        step(t + 1, xr1, mr1);
        step(t + 2, xr2, mr2);
        step(t + 3, xr3, mr3);
    }

    // epilogue: heads for the final step (t = T_STEPS-1)
    if (wv == 0) {
        const short8 oah = *(const short8*)&obh[l15][quad * 8];
        const short8 oal = *(const short8*)&obl[l15][quad * 8];
        floatx4 hacc = {0.f, 0.f, 0.f, 0.f};
        hacc = MFMA(oah, wph, hacc);
        hacc = MFMA(oal, wph, hacc);
        hacc = MFMA(oah, wpl, hacc);
        if (quad < 2) {
            const size_t rb = (size_t)(rowbase + quad * 4) * T_STEPS + (T_STEPS - 1);
            if (l15 == 0) {
#pragma unroll
                for (int r = 0; r < 4; ++r) pos_out[(rb + (size_t)r * T_STEPS) * 2 + 0] = hacc[r] + bc0;
            } else if (l15 == 1) {
#pragma unroll
                for (int r = 0; r < 4; ++r) pos_out[(rb + (size_t)r * T_STEPS) * 2 + 1] = hacc[r] + bc1;
            } else if (l15 == 2) {
#pragma unroll
                for (int r = 0; r < 4; ++r) {
                    const float z = hacc[r] + blv;
                    lv_out[rb + (size_t)r * T_STEPS] = rcp_f(1.0f + exp2f(-LOG2E * z));
                }
            }
        }
    }

    if (uact) {
        hT_out[(size_t)urow * HID + uj] = h_st;
        cT_out[(size_t)urow * HID + uj] = c_st;
    }
}

extern "C" void kernel_launch(void* const* d_in, const int* in_sizes, int n_in,
                              void* d_out, int out_size, void* d_ws, size_t ws_size,
                              hipStream_t stream) {
    const float* x     = (const float*)d_in[0];
    const float* h0    = (const float*)d_in[1];
    const float* c0    = (const float*)d_in[2];
    const float* W_ih  = (const float*)d_in[3];
    const float* W_hh  = (const float*)d_in[4];
    const float* b_ih  = (const float*)d_in[5];
    const float* b_hh  = (const float*)d_in[6];
    const float* W_all = (const float*)d_in[7];
    const float* b_all = (const float*)d_in[8];
    const float* W_pos = (const float*)d_in[9];
    const float* b_pos = (const float*)d_in[10];
    const float* W_lv  = (const float*)d_in[11];
    const float* b_lv  = (const float*)d_in[12];

    const int B = in_sizes[1] / HID;         // h0 is [1,B,H] -> 4096
    float* out     = (float*)d_out;
    float* pos_out = out;                                    // [B,T,2]
    float* lv_out  = pos_out + (size_t)B * T_STEPS * 2;      // [B,T,1]
    float* hT_out  = lv_out  + (size_t)B * T_STEPS;          // [1,B,H]
    float* cT_out  = hT_out  + (size_t)B * HID;              // [1,B,H]

    dim3 grid(B / ROWS), block(512);
    hipLaunchKernelGGL(lstm_fused_kernel, grid, block, 0, stream,
                       x, h0, c0, W_ih, W_hh, b_ih, b_hh, W_all, b_all,
                       W_pos, b_pos, W_lv, b_lv, pos_out, lv_out, hT_out, cT_out);
}

// Round 4
// 733.573 us; speedup vs baseline: 1.5077x; 1.5077x over previous
//
#include <hip/hip_runtime.h>
#include <stdint.h>

#define T_STEPS 512
#define F_IN 30
#define HID 32
#define LOG2E 1.44269504088896340736f

typedef __attribute__((ext_vector_type(8))) short short8;   // 8 bf16 (4 VGPRs)
typedef __attribute__((ext_vector_type(4))) float floatx4;  // 4 f32 acc

#define MFMA(a, b, c) __builtin_amdgcn_mfma_f32_16x16x32_bf16((a), (b), (c), 0, 0, 0)

__device__ __forceinline__ unsigned short f2bf(float f) {
    uint32_t u = __float_as_uint(f);
    u += 0x7fffu + ((u >> 16) & 1u);            // RTNE
    return (unsigned short)(u >> 16);
}
__device__ __forceinline__ float bf2f(unsigned short h) {
    return __uint_as_float(((uint32_t)h) << 16);
}
// packed f32->bf16 RTNE, single VALU op (gfx950); lo16 = S0, hi16 = S1
__device__ __forceinline__ uint32_t cvtpk(float a, float b) {
    uint32_t r;
    asm("v_cvt_pk_bf16_f32 %0, %1, %2" : "=v"(r) : "v"(a), "v"(b));
    return r;
}
__device__ __forceinline__ float rcp_f(float x) { return __builtin_amdgcn_rcpf(x); }
#if __has_builtin(__builtin_amdgcn_exp2f)
__device__ __forceinline__ float exp2_f(float x) { return __builtin_amdgcn_exp2f(x); }
#else
__device__ __forceinline__ float exp2_f(float x) { return exp2f(x); }
#endif

__device__ __forceinline__ void loadx8(float (&d)[8], const float* p, bool tail) {
    float2 a0 = *(const float2*)(p + 0);
    float2 a1 = *(const float2*)(p + 2);
    float2 a2 = *(const float2*)(p + 4);
    float2 a3 = make_float2(0.f, 0.f);
    if (!tail) a3 = *(const float2*)(p + 6);     // quad3: feats 24..29 only; slots 6,7 set at cvt
    d[0]=a0.x; d[1]=a0.y; d[2]=a1.x; d[3]=a1.y;
    d[4]=a2.x; d[5]=a2.y; d[6]=a3.x; d[7]=a3.y;
}

// One wave = one block = 16 batch rows, fully self-contained LSTM chain.
// Swapped MFMA orientation: A = weights (m = gate), B = data (n = batch row).
// Unit permutation P(c) = 8*((c&15)>>2) + 4*(c>>4) + (c&3) makes each lane's
// updated h values exactly the 8 B-frag k-slots it supplies next step:
// zero LDS, zero barriers, zero cross-lane traffic.
__global__ __launch_bounds__(64, 1)
void lstm_wave_kernel(const float* __restrict__ x, const float* __restrict__ h0,
                      const float* __restrict__ c0, const float* __restrict__ W_ih,
                      const float* __restrict__ W_hh, const float* __restrict__ b_ih,
                      const float* __restrict__ b_hh, const float* __restrict__ W_all,
                      const float* __restrict__ b_all, const float* __restrict__ W_pos,
                      const float* __restrict__ b_pos, const float* __restrict__ W_lv,
                      const float* __restrict__ b_lv, float* __restrict__ pos_out,
                      float* __restrict__ lv_out, float* __restrict__ hT_out,
                      float* __restrict__ cT_out)
{
    const int lane = threadIdx.x;     // block = 64 threads = 1 wave
    const int quad = lane >> 4;
    const int l15  = lane & 15;
    const int row  = blockIdx.x * 16 + l15;   // this lane's batch row (B-frag n, update row)

    // ---- gate weight A-frags: 8 M-tiles of 16 gate-rows, hi/lo split, exp2-folded ----
    // lane (quad,l15) tile mt holds W~[m = mt*16+l15][k = quad*8+j].
    // k slots 30/31 of the x-weights carry the bias (x slots 30/31 are set to 1.0).
    short8 wxh[8], wxl[8], whh[8], whl[8];
#pragma unroll
    for (int mt = 0; mt < 8; ++mt) {
        const float gs = ((mt == 4) || (mt == 5) ? -2.0f : -1.0f) * LOG2E;
        const int m = mt * 16 + l15;
        const int c = m & 31;
        const int u = 8 * ((c & 15) >> 2) + 4 * (c >> 4) + (c & 3);   // P(c)
        const int R = (m >> 5) * 32 + u;                              // original weight row
        const float bias = (b_ih[R] + b_hh[R]) * gs;
#pragma unroll
        for (int j = 0; j < 8; ++j) {
            const int k = quad * 8 + j;
            float wx = (k < F_IN) ? W_ih[R * F_IN + k] * gs : (k == F_IN ? bias : 0.0f);
            unsigned short hx = f2bf(wx);
            wxh[mt][j] = (short)hx; wxl[mt][j] = (short)f2bf(wx - bf2f(hx));
            float wh = W_hh[R * HID + k] * gs;
            unsigned short hh = f2bf(wh);
            whh[mt][j] = (short)hh; whl[mt][j] = (short)f2bf(wh - bf2f(hh));
        }
    }

    // ---- head A-frags: m-row 0 = pos0, 1 = pos1, 2 = leave, 3..15 = zero ----
    short8 wph, wpl;
#pragma unroll
    for (int j = 0; j < 8; ++j) {
        const int k = quad * 8 + j;   // physical hidden unit
        float w = 0.0f;
        if (l15 == 0)      { for (int o = 0; o < HID; ++o) w += W_pos[o]       * W_all[o * HID + k]; }
        else if (l15 == 1) { for (int o = 0; o < HID; ++o) w += W_pos[HID + o] * W_all[o * HID + k]; }
        else if (l15 == 2) { w = W_lv[k]; }
        unsigned short hw_ = f2bf(w);
        wph[j] = (short)hw_; wpl[j] = (short)f2bf(w - bf2f(hw_));
    }
    float bc0 = b_pos[0], bc1 = b_pos[1];
    for (int o = 0; o < HID; ++o) { bc0 += W_pos[o] * b_all[o]; bc1 += W_pos[HID + o] * b_all[o]; }
    const float blv = b_lv[0];

    // ---- state: lane owns (row, units 8*quad .. 8*quad+7) ----
    union HU { uint32_t u[4]; short8 s; };
    float cst[8];
    HU Hh, Hl;                                  // h as bf16 hi/lo pairs == next-step B-frag words
    {
        const float* hp = h0 + (size_t)row * HID + quad * 8;
        const float* cp = c0 + (size_t)row * HID + quad * 8;
        float hv[8];
#pragma unroll
        for (int j = 0; j < 8; ++j) { hv[j] = hp[j]; cst[j] = cp[j]; }
#pragma unroll
        for (int w = 0; w < 4; ++w) {
            const uint32_t ph = cvtpk(hv[2 * w], hv[2 * w + 1]);
            const float r0 = hv[2 * w]     - __uint_as_float(ph << 16);
            const float r1 = hv[2 * w + 1] - __uint_as_float(ph & 0xffff0000u);
            Hh.u[w] = ph; Hl.u[w] = cvtpk(r0, r1);
        }
    }

    // ---- x / mask prefetch ring (depth 4) ----
    const float* xlane = x + (size_t)row * T_STEPS * F_IN + quad * 8;
    const float* mptr  = x + (size_t)row * T_STEPS * F_IN + (F_IN - 1);
    const bool tail = (quad == 3);

    float xr0[8] = {0,0,0,0,0,0,0,0}, xr1[8] = {0,0,0,0,0,0,0,0};
    float xr2[8] = {0,0,0,0,0,0,0,0}, xr3[8] = {0,0,0,0,0,0,0,0};
    float mr0, mr1, mr2, mr3;
    loadx8(xr0, xlane + 0 * F_IN, tail);  mr0 = mptr[0 * F_IN];
    loadx8(xr1, xlane + 1 * F_IN, tail);  mr1 = mptr[1 * F_IN];
    loadx8(xr2, xlane + 2 * F_IN, tail);  mr2 = mptr[2 * F_IN];
    loadx8(xr3, xlane + 3 * F_IN, tail);  mr3 = mptr[3 * F_IN];

    auto step = [&](int t, float (&xr)[8], float& mr) {
        const float mcur = mr;
        // x B-frag (quad3 slots 6,7 = 1.0 bf16 -> bias via weight slots 30/31)
        HU xu;
        xu.u[0] = cvtpk(xr[0], xr[1]);
        xu.u[1] = cvtpk(xr[2], xr[3]);
        xu.u[2] = cvtpk(xr[4], xr[5]);
        xu.u[3] = tail ? 0x3f803f80u : cvtpk(xr[6], xr[7]);
        const short8 xah = xu.s;
        const short8 hah = Hh.s, hal = Hl.s;
        // prefetch t+4 into this ring slot
        {
            const int tp = (t + 4 < T_STEPS) ? t + 4 : (T_STEPS - 1);
            loadx8(xr, xlane + (size_t)tp * F_IN, tail);
            mr = mptr[(size_t)tp * F_IN];
        }
        // 8 independent gate tiles x 5 MFMAs (same hi/lo product set as before)
        floatx4 acc[8];
#pragma unroll
        for (int mt = 0; mt < 8; ++mt) {
            floatx4 a = {0.f, 0.f, 0.f, 0.f};
            a = MFMA(wxh[mt], xah, a);
            a = MFMA(wxl[mt], xah, a);
            a = MFMA(whh[mt], hah, a);
            a = MFMA(whh[mt], hal, a);
            a = MFMA(whl[mt], hah, a);
            acc[mt] = a;
        }
        // activations (exp2-folded, no fp32 division)
        float act[8][4];
#pragma unroll
        for (int mt = 0; mt < 8; ++mt) {
            const bool isg = (mt == 4) || (mt == 5);
#pragma unroll
            for (int r = 0; r < 4; ++r) {
                const float rr = rcp_f(1.0f + exp2_f(acc[mt][r]));
                act[mt][r] = isg ? fmaf(2.0f, rr, -1.0f) : rr;
            }
        }
        // lane-local state update: unit j (phys 8*quad+j): i,f,g,o at act[{0,2,4,6}+(j>>2)][j&3]
        const bool on = (mcur == 1.0f);
        float hn[8];
#pragma unroll
        for (int j = 0; j < 8; ++j) {
            const int tI = j >> 2, r = j & 3;
            const float gi = act[0 + tI][r], gf = act[2 + tI][r];
            const float gg = act[4 + tI][r], go = act[6 + tI][r];
            const float cn = gf * cst[j] + gi * gg;
            const float tn = fmaf(2.0f, rcp_f(1.0f + exp2_f(-2.0f * LOG2E * cn)), -1.0f);
            hn[j] = go * tn;
            cst[j] = on ? cn : cst[j];
        }
        // pack h_new -> bf16 hi/lo pairs; commit state and masked out-tile
        HU Oh, Ol;
#pragma unroll
        for (int w = 0; w < 4; ++w) {
            const uint32_t ph = cvtpk(hn[2 * w], hn[2 * w + 1]);
            const float r0 = hn[2 * w]     - __uint_as_float(ph << 16);
            const float r1 = hn[2 * w + 1] - __uint_as_float(ph & 0xffff0000u);
            const uint32_t pl = cvtpk(r0, r1);
            Oh.u[w] = on ? ph : 0u;
            Ol.u[w] = on ? pl : 0u;
            Hh.u[w] = on ? ph : Hh.u[w];
            Hl.u[w] = on ? pl : Hl.u[w];
        }
        // heads on the masked out-tile (C: n = row at l15; m-rows 0,1,2 land in quad0)
        floatx4 ha = {0.f, 0.f, 0.f, 0.f};
        ha = MFMA(wph, Oh.s, ha);
        ha = MFMA(wph, Ol.s, ha);
        ha = MFMA(wpl, Oh.s, ha);
        if (quad == 0) {
            const size_t o = (size_t)row * T_STEPS + t;
            *(float2*)&pos_out[o * 2] = make_float2(ha[0] + bc0, ha[1] + bc1);
            const float z = ha[2] + blv;
            lv_out[o] = rcp_f(1.0f + exp2_f(-LOG2E * z));
        }
    };

#pragma unroll 1
    for (int t = 0; t < T_STEPS; t += 4) {
        step(t + 0, xr0, mr0);
        step(t + 1, xr1, mr1);
        step(t + 2, xr2, mr2);
        step(t + 3, xr3, mr3);
    }

    // final state: reconstruct fp32 h from hi+lo (error ~2^-18, well under tolerance)
    {
        float* hp = hT_out + (size_t)row * HID + quad * 8;
        float* cp = cT_out + (size_t)row * HID + quad * 8;
#pragma unroll
        for (int w = 0; w < 4; ++w) {
            hp[2 * w]     = __uint_as_float(Hh.u[w] << 16)        + __uint_as_float(Hl.u[w] << 16);
            hp[2 * w + 1] = __uint_as_float(Hh.u[w] & 0xffff0000u) + __uint_as_float(Hl.u[w] & 0xffff0000u);
        }
#pragma unroll
        for (int j = 0; j < 8; ++j) cp[j] = cst[j];
    }
}

extern "C" void kernel_launch(void* const* d_in, const int* in_sizes, int n_in,
                              void* d_out, int out_size, void* d_ws, size_t ws_size,
                              hipStream_t stream) {
    const float* x     = (const float*)d_in[0];
    const float* h0    = (const float*)d_in[1];
    const float* c0    = (const float*)d_in[2];
    const float* W_ih  = (const float*)d_in[3];
    const float* W_hh  = (const float*)d_in[4];
    const float* b_ih  = (const float*)d_in[5];
    const float* b_hh  = (const float*)d_in[6];
    const float* W_all = (const float*)d_in[7];
    const float* b_all = (const float*)d_in[8];
    const float* W_pos = (const float*)d_in[9];
    const float* b_pos = (const float*)d_in[10];
    const float* W_lv  = (const float*)d_in[11];
    const float* b_lv  = (const float*)d_in[12];

    const int B = in_sizes[1] / HID;         // h0 is [1,B,H] -> 4096
    float* out     = (float*)d_out;
    float* pos_out = out;                                    // [B,T,2]
    float* lv_out  = pos_out + (size_t)B * T_STEPS * 2;      // [B,T,1]
    float* hT_out  = lv_out  + (size_t)B * T_STEPS;          // [1,B,H]
    float* cT_out  = hT_out  + (size_t)B * HID;              // [1,B,H]

    dim3 grid(B / 16), block(64);
    hipLaunchKernelGGL(lstm_wave_kernel, grid, block, 0, stream,
                       x, h0, c0, W_ih, W_hh, b_ih, b_hh, W_all, b_all,
                       W_pos, b_pos, W_lv, b_lv, pos_out, lv_out, hT_out, cT_out);
}